// Round 14
// baseline (1111.603 us; speedup 1.0000x reference)
//
#include <hip/hip_runtime.h>

// GCN 2-layer forward on MI355X.
// Pipeline: decode edges -> CSR(count/scan/dinv/fill col-only) -> xconv(dinv-scaled bf16)
//   -> agg128 -> MFMA-gemm1(+b1+relu, dinv-scaled bf16 out) -> agg256<0>,<1> -> MFMA-gemm2.
// Established: agg kernels are L2-fill-line-bound (R8 depth flat, R9 store policy flat,
//   R11 bytes halved -> time halved; R13 FETCH=1.45 lines/cyc/XCD ~ fill-port ceiling).
// R13: (a) feature-split agg256 into two 128-wide passes (footprint 51->25.6MB per pass,
//   raise L2 hit rate -> fewer fill transactions); (b) fold dinv into stored features:
//   out[v]=dinv[v]*(sum s_h[src] + s_h[v]), s_h=dinv*h -> edge array is col-only int32
//   (12.8MB, read 2x = neutral), inner loop pure adds.

#define DF 256  // GEMM output width (both layers)

typedef float f4v __attribute__((ext_vector_type(4)));
typedef float f2v __attribute__((ext_vector_type(2)));
typedef short bf16x8 __attribute__((ext_vector_type(8)));
typedef float f32x4 __attribute__((ext_vector_type(4)));

__device__ inline void nt_store4(float* p, float4 v) {
  f4v t;
  t.x = v.x; t.y = v.y; t.z = v.z; t.w = v.w;
  __builtin_nontemporal_store(t, (f4v*)p);
}
__device__ inline void nt_store2(float* p, float a, float b) {
  f2v t;
  t.x = a; t.y = b;
  __builtin_nontemporal_store(t, (f2v*)p);
}
__device__ inline unsigned short f2bf(float f) {  // round-to-nearest-even
  unsigned u = __float_as_uint(f);
  return (unsigned short)((u + 0x7FFFu + ((u >> 16) & 1u)) >> 16);
}
__device__ inline float bf2f(unsigned short h) {
  return __uint_as_float(((unsigned)h) << 16);
}

// ---------------- utility ----------------
__global__ __launch_bounds__(256) void zero_i32(int* __restrict__ p, int n) {
  int i = blockIdx.x * blockDim.x + threadIdx.x;
  if (i < n) p[i] = 0;
}

// ---------------- edge_index dtype detection (int64 vs int32) ----------------
__global__ __launch_bounds__(256) void detect_kernel(const int* __restrict__ ei32,
                                                     int n_logical,
                                                     int* __restrict__ flag) {
  __shared__ int s_nonzero;
  if (threadIdx.x == 0) s_nonzero = 0;
  __syncthreads();
  const int n_half = n_logical >> 1;
  int step = n_half / 1024;
  if (step < 1) step = 1;
  for (int k = threadIdx.x; k < 1024; k += 256) {
    long idx = (long)k * step;
    if (idx < n_half && ei32[2 * idx + 1] != 0) atomicOr(&s_nonzero, 1);
  }
  __syncthreads();
  if (threadIdx.x == 0) flag[0] = s_nonzero ? 0 : 1;  // 1 => int64
}

// ---------------- decode to canonical int32 ----------------
__global__ __launch_bounds__(256) void convert_kernel(const int* __restrict__ ei32,
                                                      const int* __restrict__ flag,
                                                      int* __restrict__ conv, int n) {
  int i = blockIdx.x * blockDim.x + threadIdx.x;
  if (i < n) conv[i] = flag[0] ? ei32[2 * (size_t)i] : ei32[i];
}

// ---------------- x -> dinv-scaled bf16 (8 elems/thread) ----------------
__global__ __launch_bounds__(256) void xconv_kernel(const float* __restrict__ x,
                                                    const float* __restrict__ dinv,
                                                    unsigned short* __restrict__ xb,
                                                    int n8) {
  int i = blockIdx.x * blockDim.x + threadIdx.x;
  if (i < n8) {
    float di = dinv[i / 16];  // row = i*8/128
    const float4 v0 = *(const float4*)&x[(size_t)i * 8];
    const float4 v1 = *(const float4*)&x[(size_t)i * 8 + 4];
    unsigned p0 = f2bf(di * v0.x) | ((unsigned)f2bf(di * v0.y) << 16);
    unsigned p1 = f2bf(di * v0.z) | ((unsigned)f2bf(di * v0.w) << 16);
    unsigned p2 = f2bf(di * v1.x) | ((unsigned)f2bf(di * v1.y) << 16);
    unsigned p3 = f2bf(di * v1.z) | ((unsigned)f2bf(di * v1.w) << 16);
    *(uint4*)&xb[(size_t)i * 8] = make_uint4(p0, p1, p2, p3);
  }
}

// ---------------- W[K,256] fp32 -> Wt[256][K] bf16 (transpose+convert) ----------------
__global__ __launch_bounds__(256) void wconv_kernel(const float* __restrict__ W,
                                                    unsigned short* __restrict__ Wt, int K) {
  int idx = blockIdx.x * blockDim.x + threadIdx.x;
  if (idx < K * 256) {
    int k = idx / 256, c = idx % 256;
    Wt[c * K + k] = f2bf(W[idx]);
  }
}

// ---------------- degree histogram ----------------
__global__ __launch_bounds__(256) void count_kernel(const int* __restrict__ dst,
                                                    int* __restrict__ cnt, int E, int n) {
  int i = blockIdx.x * blockDim.x + threadIdx.x;
  if (i < E) {
    int d = dst[i];
    if ((unsigned)d < (unsigned)n) atomicAdd(&cnt[d], 1);
  }
}

// ---------------- single-block exclusive scan over n counts ----------------
__global__ __launch_bounds__(1024) void scan_kernel(const int* __restrict__ cnt,
                                                    int* __restrict__ row_ptr, int n) {
  __shared__ int wsum[16];
  __shared__ int s_base;
  const int tid = threadIdx.x;
  const int lane = tid & 63;
  const int wid = tid >> 6;
  if (tid == 0) s_base = 0;
  __syncthreads();
  for (int start = 0; start < n; start += 4096) {
    const int i0 = start + tid * 4;
    int v[4];
#pragma unroll
    for (int u = 0; u < 4; ++u) v[u] = (i0 + u < n) ? cnt[i0 + u] : 0;
    const int tsum = v[0] + v[1] + v[2] + v[3];
    int sc = tsum;
#pragma unroll
    for (int off = 1; off < 64; off <<= 1) {
      int t = __shfl_up(sc, off);
      if (lane >= off) sc += t;
    }
    if (lane == 63) wsum[wid] = sc;
    __syncthreads();
    if (wid == 0) {
      int ws = (lane < 16) ? wsum[lane] : 0;
#pragma unroll
      for (int off = 1; off < 16; off <<= 1) {
        int t = __shfl_up(ws, off);
        if (lane >= off) ws += t;
      }
      if (lane < 16) wsum[lane] = ws;
    }
    __syncthreads();
    int base = s_base + (wid > 0 ? wsum[wid - 1] : 0) + (sc - tsum);
#pragma unroll
    for (int u = 0; u < 4; ++u) {
      if (i0 + u < n) row_ptr[i0 + u] = base;
      base += v[u];
    }
    __syncthreads();
    if (tid == 1023) s_base += wsum[15];
    __syncthreads();
  }
  if (tid == 0) row_ptr[n] = s_base;
}

// ---------------- dinv = rsqrt(deg+1), cursor = row_ptr copy ----------------
__global__ __launch_bounds__(256) void dinv_cursor_kernel(const int* __restrict__ cnt,
                                                          const int* __restrict__ row_ptr,
                                                          float* __restrict__ dinv,
                                                          int* __restrict__ cursor, int n) {
  int i = blockIdx.x * blockDim.x + threadIdx.x;
  if (i < n) {
    dinv[i] = rsqrtf((float)(cnt[i] + 1));
    cursor[i] = row_ptr[i];
  }
}

// ---------------- CSR fill: col[] only (weights folded into features) ----------------
__global__ __launch_bounds__(256) void fill_kernel(const int* __restrict__ src,
                                                   const int* __restrict__ dst,
                                                   int* __restrict__ cursor,
                                                   int* __restrict__ col, int E, int n) {
  int i = blockIdx.x * blockDim.x + threadIdx.x;
  if (i < E) {
    int s = src[i], d = dst[i];
    if ((unsigned)s < (unsigned)n && (unsigned)d < (unsigned)n) {
      int pos = atomicAdd(&cursor[d], 1);
      col[pos] = s;
    }
  }
}

// ---------------- MFMA bf16 GEMM: out = X[M,K](fp32) @ Wt(bf16) + b ----------------
// OBF16 path also scales rows by dinv (layer-1: emit s_h = dinv*relu(...)).
template <int K, bool RELU, bool OBF16>
__global__ __launch_bounds__(256) void gemm_kernel(const float* __restrict__ X,
                                                   const unsigned short* __restrict__ Wt,
                                                   const float* __restrict__ bias,
                                                   const float* __restrict__ dinv,
                                                   void* __restrict__ outv, int M) {
  __shared__ unsigned short as_[32 * K];
  const int t = threadIdx.x;
  const int row0 = blockIdx.x * 32;

  for (int i = t; i < 4 * K; i += 256) {  // 32 rows * K/8 chunks
    int r = i / (K / 8);
    int kk = (i % (K / 8)) * 8;
    int gr = row0 + r;
    float4 v0 = make_float4(0.f, 0.f, 0.f, 0.f), v1 = v0;
    if (gr < M) {
      v0 = *(const float4*)&X[(size_t)gr * K + kk];
      v1 = *(const float4*)&X[(size_t)gr * K + kk + 4];
    }
    unsigned p0 = f2bf(v0.x) | ((unsigned)f2bf(v0.y) << 16);
    unsigned p1 = f2bf(v0.z) | ((unsigned)f2bf(v0.w) << 16);
    unsigned p2 = f2bf(v1.x) | ((unsigned)f2bf(v1.y) << 16);
    unsigned p3 = f2bf(v1.z) | ((unsigned)f2bf(v1.w) << 16);
    unsigned byte = (unsigned)((r * K + kk) * 2) ^ ((unsigned)(r & 7) << 4);
    *(uint4*)((char*)as_ + byte) = make_uint4(p0, p1, p2, p3);
  }
  __syncthreads();

  const int l = t & 63;
  const int wv = t >> 6;
  const int lc = l & 15;
  const int lk = (l >> 4) * 8;

  f32x4 acc[2][4];
#pragma unroll
  for (int i = 0; i < 2; ++i)
#pragma unroll
    for (int j = 0; j < 4; ++j) acc[i][j] = (f32x4)0.f;

#pragma unroll
  for (int ks = 0; ks < K / 32; ++ks) {
    bf16x8 a[2];
#pragma unroll
    for (int mrep = 0; mrep < 2; ++mrep) {
      int row = mrep * 16 + lc;
      unsigned byte = (unsigned)((row * K + ks * 32 + lk) * 2) ^ ((unsigned)(row & 7) << 4);
      a[mrep] = *(const bf16x8*)((const char*)as_ + byte);
    }
    bf16x8 b[4];
#pragma unroll
    for (int nf = 0; nf < 4; ++nf) {
      int col = wv * 64 + nf * 16 + lc;
      b[nf] = *(const bf16x8*)&Wt[(size_t)col * K + ks * 32 + lk];
    }
#pragma unroll
    for (int mrep = 0; mrep < 2; ++mrep)
#pragma unroll
      for (int nf = 0; nf < 4; ++nf)
        acc[mrep][nf] = __builtin_amdgcn_mfma_f32_16x16x32_bf16(a[mrep], b[nf], acc[mrep][nf], 0, 0, 0);
  }

#pragma unroll
  for (int nf = 0; nf < 4; ++nf) {
    int gcol = wv * 64 + nf * 16 + lc;
    float bv = bias[gcol];
#pragma unroll
    for (int mrep = 0; mrep < 2; ++mrep) {
#pragma unroll
      for (int r = 0; r < 4; ++r) {
        int grow = row0 + mrep * 16 + (l >> 4) * 4 + r;
        if (grow < M) {
          float val = acc[mrep][nf][r] + bv;
          if (RELU) val = fmaxf(val, 0.f);
          if (OBF16) {
            val *= dinv[grow];  // emit s_h = dinv * relu(...)
            ((unsigned short*)outv)[(size_t)grow * DF + gcol] = f2bf(val);
          } else {
            ((float*)outv)[(size_t)grow * DF + gcol] = val;
          }
        }
      }
    }
  }
}

// ---------------- agg256 half-pass: out[v][f] = dinv[v]*(sum hb[col][f] + hb[v][f]) ----------------
// HALF selects features [HALF*128, HALF*128+128); lane covers 2 features (ushort2).
template <int HALF>
__global__ __launch_bounds__(256) void agg256_kernel(const unsigned short* __restrict__ hb,
                                                     const int* __restrict__ row_ptr,
                                                     const int* __restrict__ col,
                                                     const float* __restrict__ dinv,
                                                     float* __restrict__ out, int n) {
  int wid = (blockIdx.x * blockDim.x + threadIdx.x) >> 6;
  int lane = threadIdx.x & 63;
  if (wid >= n) return;
  int start = row_ptr[wid];
  int end = row_ptr[wid + 1];
  const int foff = HALF * 128 + lane * 2;

  float ax = 0.f, ay = 0.f;
  for (int base = start; base < end; base += 64) {
    int e = base + lane;
    int ce = 0;
    if (e < end) ce = __builtin_nontemporal_load(&col[e]);
    int m = end - base;
    if (m > 64) m = 64;
    int j = 0;
    for (; j + 16 <= m; j += 16) {
      ushort2 hq[16];
#pragma unroll
      for (int u = 0; u < 16; ++u) {
        int s = __shfl(ce, j + u);
        hq[u] = *(const ushort2*)&hb[(size_t)s * 256 + foff];
      }
#pragma unroll
      for (int u = 0; u < 16; ++u) {
        ax += bf2f(hq[u].x);
        ay += bf2f(hq[u].y);
      }
    }
    for (; j < m; ++j) {
      int s = __shfl(ce, j);
      ushort2 hq = *(const ushort2*)&hb[(size_t)s * 256 + foff];
      ax += bf2f(hq.x);
      ay += bf2f(hq.y);
    }
  }
  float di = dinv[wid];
  ushort2 own = *(const ushort2*)&hb[(size_t)wid * 256 + foff];
  nt_store2(&out[(size_t)wid * 256 + foff], di * (ax + bf2f(own.x)), di * (ay + bf2f(own.y)));
}

// ---------------- agg128: half-wave per edge; out = dinv[v]*(sum xb[col] + xb[v]) ----------------
__global__ __launch_bounds__(256) void agg128_kernel(const unsigned short* __restrict__ xb,
                                                     const int* __restrict__ row_ptr,
                                                     const int* __restrict__ col,
                                                     const float* __restrict__ dinv,
                                                     float* __restrict__ out, int n) {
  int wid = (blockIdx.x * blockDim.x + threadIdx.x) >> 6;
  int lane = threadIdx.x & 63;
  if (wid >= n) return;
  int start = row_ptr[wid];
  int end = row_ptr[wid + 1];
  const int half = lane >> 5;
  const int foff = (lane & 31) * 4;

  float4 acc = make_float4(0.f, 0.f, 0.f, 0.f);
  for (int base = start; base < end; base += 64) {
    int e = base + lane;
    int ce = 0;
    if (e < end) ce = __builtin_nontemporal_load(&col[e]);
    int m = end - base;
    if (m > 64) m = 64;
    int j = 0;
    for (; j + 32 <= m; j += 32) {
      ushort4 hq[16];
#pragma unroll
      for (int u = 0; u < 16; ++u) {
        int s = __shfl(ce, j + 2 * u + half);
        hq[u] = *(const ushort4*)&xb[(size_t)s * 128 + foff];
      }
#pragma unroll
      for (int u = 0; u < 16; ++u) {
        acc.x += bf2f(hq[u].x);
        acc.y += bf2f(hq[u].y);
        acc.z += bf2f(hq[u].z);
        acc.w += bf2f(hq[u].w);
      }
    }
    for (; j + 2 <= m; j += 2) {
      int s = __shfl(ce, j + half);
      ushort4 hq = *(const ushort4*)&xb[(size_t)s * 128 + foff];
      acc.x += bf2f(hq.x);
      acc.y += bf2f(hq.y);
      acc.z += bf2f(hq.z);
      acc.w += bf2f(hq.w);
    }
    if (j < m) {
      int s = __shfl(ce, j);
      if (half == 0) {
        ushort4 hq = *(const ushort4*)&xb[(size_t)s * 128 + foff];
        acc.x += bf2f(hq.x);
        acc.y += bf2f(hq.y);
        acc.z += bf2f(hq.z);
        acc.w += bf2f(hq.w);
      }
    }
  }
  acc.x += __shfl_xor(acc.x, 32);
  acc.y += __shfl_xor(acc.y, 32);
  acc.z += __shfl_xor(acc.z, 32);
  acc.w += __shfl_xor(acc.w, 32);
  if (half == 0) {
    float di = dinv[wid];
    ushort4 own = *(const ushort4*)&xb[(size_t)wid * 128 + foff];
    float4 res;
    res.x = di * (acc.x + bf2f(own.x));
    res.y = di * (acc.y + bf2f(own.y));
    res.z = di * (acc.z + bf2f(own.z));
    res.w = di * (acc.w + bf2f(own.w));
    nt_store4(&out[(size_t)wid * 128 + foff], res);
  }
}

// ---------------- launch ----------------
extern "C" void kernel_launch(void* const* d_in, const int* in_sizes, int n_in,
                              void* d_out, int out_size, void* d_ws, size_t ws_size,
                              hipStream_t stream) {
  const float* x = (const float*)d_in[0];
  const int* ei = (const int*)d_in[1];
  const float* W1 = (const float*)d_in[2];
  const float* b1 = (const float*)d_in[3];
  const float* W2 = (const float*)d_in[4];
  const float* b2 = (const float*)d_in[5];

  const int N = in_sizes[0] / 128;   // 100000
  const int NE2 = in_sizes[1];       // 2*E logical int elements
  const int E = NE2 / 2;             // 3200000

  // workspace carve (256B aligned); ~117MB
  char* p = (char*)d_ws;
  auto carve = [&](size_t bytes) {
    void* q = (void*)p;
    p += (bytes + 255) & ~(size_t)255;
    return q;
  };
  int* flag = (int*)carve(4);
  int* cnt = (int*)carve((size_t)N * 4);
  int* row_ptr = (int*)carve((size_t)(N + 1) * 4);
  int* cursor = (int*)carve((size_t)N * 4);
  float* dinv = (float*)carve((size_t)N * 4);
  int* col = (int*)carve((size_t)E * 4);  // col-only edge array (R13)
  unsigned short* Wt1 = (unsigned short*)carve(128 * 256 * 2);
  unsigned short* Wt2 = (unsigned short*)carve(256 * 256 * 2);
  float* buf = (float*)carve((size_t)N * DF * 4);  // 102.4MB; ax & ah (fp32)
  int* conv = (int*)buf;  // decoded edges alias buf head (dead before agg128)
  const int* src = conv;
  const int* dst = conv + E;
  // d_out layout during pipeline: [0,51.2MB) hb bf16; [51.2,76.8MB) xb bf16.
  unsigned short* hb = (unsigned short*)d_out;
  unsigned short* xb = (unsigned short*)((char*)d_out + (size_t)N * 256 * 2);

  // ---- decode edges; CSR build (dinv needed before xconv) ----
  detect_kernel<<<1, 256, 0, stream>>>(ei, NE2, flag);
  convert_kernel<<<(NE2 + 255) / 256, 256, 0, stream>>>(ei, flag, conv, NE2);
  zero_i32<<<(N + 255) / 256, 256, 0, stream>>>(cnt, N);
  count_kernel<<<(E + 255) / 256, 256, 0, stream>>>(dst, cnt, E, N);
  scan_kernel<<<1, 1024, 0, stream>>>(cnt, row_ptr, N);
  dinv_cursor_kernel<<<(N + 255) / 256, 256, 0, stream>>>(cnt, row_ptr, dinv, cursor, N);
  fill_kernel<<<(E + 255) / 256, 256, 0, stream>>>(src, dst, cursor, col, E, N);

  // ---- dtype conversions (xb = dinv-scaled bf16 x) ----
  xconv_kernel<<<(N * 128 / 8 + 255) / 256, 256, 0, stream>>>(x, dinv, xb, N * 128 / 8);
  wconv_kernel<<<(128 * 256 + 255) / 256, 256, 0, stream>>>(W1, Wt1, 128);
  wconv_kernel<<<(256 * 256 + 255) / 256, 256, 0, stream>>>(W2, Wt2, 256);

  const int agg_blocks = (N * 64 + 255) / 256;

  // ---- layer 1: ax = dinv*(sum xb + own) ; hb = dinv*bf16(relu(ax@W1+b1)) ----
  agg128_kernel<<<agg_blocks, 256, 0, stream>>>(xb, row_ptr, col, dinv, buf, N);
  gemm_kernel<128, true, true><<<(N + 31) / 32, 256, 0, stream>>>(buf, Wt1, b1, dinv, hb, N);

  // ---- layer 2: ah = dinv*(sum hb + own), two feature-half passes ; out = ah@W2+b2 ----
  agg256_kernel<0><<<agg_blocks, 256, 0, stream>>>(hb, row_ptr, col, dinv, buf, N);
  agg256_kernel<1><<<agg_blocks, 256, 0, stream>>>(hb, row_ptr, col, dinv, buf, N);
  gemm_kernel<256, false, false><<<(N + 31) / 32, 256, 0, stream>>>(buf, Wt2, b2, dinv, d_out, N);
}